// Round 2
// baseline (573.730 us; speedup 1.0000x reference)
//
#include <hip/hip_runtime.h>
#include <hip/hip_bf16.h>

// EdgeAttentionEmbedding collapsed form:
//   softmax([s,s]) == [0.5,0.5]  =>  attention branch (W2,b2,Wa,ba) is dead.
//   out[e] = row_softmax( a_e*(nf[u]+nf[v]) @ A + ef[e] @ Bm + c )
//   A  = 0.5*sum_h W1_h @ W3_h[:128]   (128x128)
//   Bm = 0.5*sum_h W3_h[128:192]       (64x128)
//   c  = sum_h b1_h @ W3_h[:128] + 0.5*sum_h b3_h
//   a_e = (u==v) ? 1.0 : 0.5
// y = nf @ A precomputed over N=50k nodes. Edge kernel: ef@Bm via MFMA,
// LDS-transpose epilogue (4 lanes/edge x 32 contiguous cols) so y-gathers,
// softmax, and stores are all float4 / coalesced.

#define NNODES 50000
#define NEDGES 640000

typedef __bf16 bf16;
typedef __bf16 bf16x4 __attribute__((ext_vector_type(4)));
typedef __bf16 bf16x8 __attribute__((ext_vector_type(8)));
typedef float f32x4 __attribute__((ext_vector_type(4)));

// ---------------------------------------------------------------- kernel 0
// Fold weights: At[c][k] = A[k][c] (bf16), Bmt[c][k] = Bm[k][c] (bf16), cvec f32.
__global__ void prep_kernel(const float* __restrict__ W1, const float* __restrict__ b1,
                            const float* __restrict__ W3, const float* __restrict__ b3,
                            bf16* __restrict__ At, bf16* __restrict__ Bmt,
                            float* __restrict__ cvec) {
    int j = threadIdx.x;   // output column 0..127
    int i = blockIdx.x;    // 0..127: A row i; 128: c + Bmt
    if (i < 128) {
        float acc = 0.f;
        for (int h = 0; h < 2; ++h) {
            const float* w1 = W1 + h * 128 * 128 + i * 128;
            const float* w3 = W3 + h * 192 * 128;
            for (int k = 0; k < 128; ++k)
                acc += w1[k] * w3[k * 128 + j];
        }
        At[j * 128 + i] = (bf16)(0.5f * acc);
    } else {
        float acc = 0.f;
        for (int h = 0; h < 2; ++h) {
            const float* w3 = W3 + h * 192 * 128;
            for (int k = 0; k < 128; ++k)
                acc += b1[h * 128 + k] * w3[k * 128 + j];
        }
        acc += 0.5f * (b3[j] + b3[128 + j]);
        cvec[j] = acc;
        for (int k = 0; k < 64; ++k) {
            float bm = 0.5f * (W3[(128 + k) * 128 + j] +
                               W3[192 * 128 + (128 + k) * 128 + j]);
            Bmt[j * 64 + k] = (bf16)bm;
        }
    }
}

// ---------------------------------------------------------------- kernel 1
// y[n][c] = (nf @ A)[n][c], fp32 out. Tile: 64 rows x 128 cols per block (4 waves).
#define K1_PAD 136   // 128 + 8 shorts: 272B rows (16B aligned)

__global__ __launch_bounds__(256) void node_proj_kernel(
        const float* __restrict__ nf, const bf16* __restrict__ At_g,
        float* __restrict__ y) {
    __shared__ bf16 a_lds[64 * K1_PAD];
    __shared__ bf16 b_lds[128 * K1_PAD];
    const int t = threadIdx.x;
    const int m0 = blockIdx.x * 64;
    for (int it = 0; it < 8; ++it) {
        int f4 = it * 256 + t;              // 2048 float4 = 64 rows x 32
        int row = f4 >> 5, k4 = (f4 & 31) * 4;
        int g = m0 + row; if (g > NNODES - 1) g = NNODES - 1;
        float4 v = ((const float4*)(nf + (size_t)g * 128))[f4 & 31];
        *(bf16x4*)&a_lds[row * K1_PAD + k4] =
            (bf16x4){(bf16)v.x, (bf16)v.y, (bf16)v.z, (bf16)v.w};
    }
    for (int it = 0; it < 8; ++it) {
        int c8 = it * 256 + t;              // 2048 chunks of 8 shorts
        int row = c8 >> 4, k8 = (c8 & 15) * 8;
        *(int4*)&b_lds[row * K1_PAD + k8] = *(const int4*)&At_g[row * 128 + k8];
    }
    __syncthreads();
    const int wave = t >> 6, lane = t & 63;
    const int n16 = lane & 15, quad = lane >> 4;
    const int mrow = wave * 16 + n16;
    f32x4 acc[8];
#pragma unroll
    for (int ct = 0; ct < 8; ++ct) acc[ct] = (f32x4){0.f, 0.f, 0.f, 0.f};
#pragma unroll
    for (int kt = 0; kt < 4; ++kt) {
        bf16x8 a = *(const bf16x8*)&a_lds[mrow * K1_PAD + kt * 32 + quad * 8];
#pragma unroll
        for (int ct = 0; ct < 8; ++ct) {
            bf16x8 b = *(const bf16x8*)&b_lds[(ct * 16 + n16) * K1_PAD + kt * 32 + quad * 8];
            acc[ct] = __builtin_amdgcn_mfma_f32_16x16x32_bf16(a, b, acc[ct], 0, 0, 0);
        }
    }
#pragma unroll
    for (int ct = 0; ct < 8; ++ct)
#pragma unroll
        for (int r = 0; r < 4; ++r) {
            int g = m0 + wave * 16 + quad * 4 + r;
            if (g < NNODES) y[(size_t)g * 128 + ct * 16 + n16] = acc[ct][r];
        }
}

// ---------------------------------------------------------------- kernel 2
// 64 edges/block. ef@Bm via MFMA -> LDS f32 tile (+c); re-map to 4 lanes/edge
// x 32 contiguous cols for float4 y-gathers + softmax; coalesced f4 stores.
#define K2_PAD 72    // shorts per bf16 tile row
#define S_PAD 132    // floats per s-tile row (4-bank rotation: 2-way = free)

__global__ __launch_bounds__(256) void edge_kernel(
        const float* __restrict__ ef, const int* __restrict__ eidx,
        const bf16* __restrict__ Bmt_g, const float* __restrict__ cvec,
        const float* __restrict__ y, float* __restrict__ out) {
    __shared__ float s_lds[64 * S_PAD];     // 33792 B; front 9216 B doubles as ef tile
    __shared__ bf16 b_lds[128 * K2_PAD];    // 18432 B  (total 52 KB -> 3 blocks/CU)
    bf16* ef_lds = (bf16*)s_lds;
    const int t = threadIdx.x;
    const int e0 = blockIdx.x * 64;
    // stage Bmt (16 KB, L2-resident broadcast)
    for (int it = 0; it < 4; ++it) {
        int c8 = it * 256 + t;              // 1024 chunks of 8 shorts
        int row = c8 >> 3, k8 = (c8 & 7) * 8;
        *(int4*)&b_lds[row * K2_PAD + k8] = *(const int4*)&Bmt_g[row * 64 + k8];
    }
    // stage ef tile (fp32 -> bf16) into the s_lds overlay
    for (int it = 0; it < 4; ++it) {
        int f4 = it * 256 + t;              // 1024 float4 = 64 rows x 16
        int row = f4 >> 4, k4 = (f4 & 15) * 4;
        float4 v = ((const float4*)(ef + (size_t)(e0 + row) * 64))[f4 & 15];
        *(bf16x4*)&ef_lds[row * K2_PAD + k4] =
            (bf16x4){(bf16)v.x, (bf16)v.y, (bf16)v.z, (bf16)v.w};
    }
    __syncthreads();
    const int wave = t >> 6, lane = t & 63;
    const int n16 = lane & 15, quad = lane >> 4;
    const int mrow = wave * 16 + n16;
    f32x4 acc[8];
#pragma unroll
    for (int ct = 0; ct < 8; ++ct) acc[ct] = (f32x4){0.f, 0.f, 0.f, 0.f};
#pragma unroll
    for (int kt = 0; kt < 2; ++kt) {
        bf16x8 a = *(const bf16x8*)&ef_lds[mrow * K2_PAD + kt * 32 + quad * 8];
#pragma unroll
        for (int ct = 0; ct < 8; ++ct) {
            bf16x8 b = *(const bf16x8*)&b_lds[(ct * 16 + n16) * K2_PAD + kt * 32 + quad * 8];
            acc[ct] = __builtin_amdgcn_mfma_f32_16x16x32_bf16(a, b, acc[ct], 0, 0, 0);
        }
    }
    float creg[8];
#pragma unroll
    for (int ct = 0; ct < 8; ++ct) creg[ct] = cvec[ct * 16 + n16];
    __syncthreads();                         // ef tile reads complete
    // D layout: row = wave*16 + quad*4 + r, col = ct*16 + n16
#pragma unroll
    for (int ct = 0; ct < 8; ++ct)
#pragma unroll
        for (int r = 0; r < 4; ++r)
            s_lds[(wave * 16 + quad * 4 + r) * S_PAD + ct * 16 + n16] =
                acc[ct][r] + creg[ct];
    __syncthreads();
    // epilogue: 4 lanes per edge, 32 contiguous cols per lane
    const int el = t >> 2, seg = t & 3;
    const int u = eidx[e0 + el], v = eidx[NEDGES + e0 + el];
    const float a_e = (u == v) ? 1.0f : 0.5f;
    const float4* yu = (const float4*)(y + (size_t)u * 128 + seg * 32);
    const float4* yv = (const float4*)(y + (size_t)v * 128 + seg * 32);
    float l[32];
    float m = -1e30f;
#pragma unroll
    for (int j = 0; j < 8; ++j) {
        float4 sv = *(const float4*)&s_lds[el * S_PAD + seg * 32 + j * 4];
        float4 uu = yu[j];
        float4 vv = yv[j];
        l[j * 4 + 0] = sv.x + a_e * (uu.x + vv.x);
        l[j * 4 + 1] = sv.y + a_e * (uu.y + vv.y);
        l[j * 4 + 2] = sv.z + a_e * (uu.z + vv.z);
        l[j * 4 + 3] = sv.w + a_e * (uu.w + vv.w);
#pragma unroll
        for (int q = 0; q < 4; ++q) m = fmaxf(m, l[j * 4 + q]);
    }
    m = fmaxf(m, __shfl_xor(m, 1));
    m = fmaxf(m, __shfl_xor(m, 2));
    float s = 0.f;
#pragma unroll
    for (int j = 0; j < 32; ++j) { l[j] = __expf(l[j] - m); s += l[j]; }
    s += __shfl_xor(s, 1);
    s += __shfl_xor(s, 2);
    const float inv = 1.0f / s;
#pragma unroll
    for (int j = 0; j < 8; ++j) {
        float4 p;
        p.x = l[j * 4 + 0] * inv;
        p.y = l[j * 4 + 1] * inv;
        p.z = l[j * 4 + 2] * inv;
        p.w = l[j * 4 + 3] * inv;
        *(float4*)&s_lds[el * S_PAD + seg * 32 + j * 4] = p;
    }
    __syncthreads();
    // coalesced stores: 1 KB per wave-instruction
#pragma unroll
    for (int it = 0; it < 8; ++it) {
        int f4 = it * 256 + t;              // 2048 float4 = 64 rows x 32
        int row = f4 >> 5, c4 = (f4 & 31) * 4;
        *(float4*)&out[(size_t)(e0 + row) * 128 + c4] =
            *(const float4*)&s_lds[row * S_PAD + c4];
    }
}

// ---------------------------------------------------------------- launch
extern "C" void kernel_launch(void* const* d_in, const int* in_sizes, int n_in,
                              void* d_out, int out_size, void* d_ws, size_t ws_size,
                              hipStream_t stream) {
    (void)in_sizes; (void)n_in; (void)out_size; (void)ws_size;
    const float* nf  = (const float*)d_in[0];
    const float* ef  = (const float*)d_in[1];
    const int*  eidx = (const int*)d_in[2];
    const float* W1  = (const float*)d_in[3];
    const float* b1  = (const float*)d_in[4];
    // d_in[5] (W2), d_in[6] (b2), d_in[9] (Wa), d_in[10] (ba): dead in reference
    const float* W3  = (const float*)d_in[7];
    const float* b3  = (const float*)d_in[8];
    float* out = (float*)d_out;

    char* ws = (char*)d_ws;
    float* y    = (float*)ws;                                    // 25.6 MB
    bf16*  At   = (bf16*)(ws + 26u * 1024 * 1024);               // 32 KB
    bf16*  Bmt  = (bf16*)(ws + 26u * 1024 * 1024 + 64 * 1024);   // 16 KB
    float* cvec = (float*)(ws + 26u * 1024 * 1024 + 96 * 1024);  // 512 B

    prep_kernel<<<129, 128, 0, stream>>>(W1, b1, W3, b3, At, Bmt, cvec);
    node_proj_kernel<<<(NNODES + 63) / 64, 256, 0, stream>>>(nf, At, y);
    edge_kernel<<<NEDGES / 64, 256, 0, stream>>>(ef, eidx, Bmt, cvec, y, out);
}